// Round 1
// baseline (6276.106 us; speedup 1.0000x reference)
//
#include <hip/hip_runtime.h>
#include <cstdint>

// PicoGPT forward: V=32000 D=1024 DK=DV=64 H=16 DH=4096 L=8, input [2,1024]
// Strategy: bf16 MFMA GEMMs (f32 accum) for all matmuls; f32 LN/softmax/residual.

#define DEVI __device__ __forceinline__
#define NEG_INF (-__builtin_inff())

typedef __attribute__((ext_vector_type(8))) short s8v;  // 8 x bf16 (4 VGPRs)
typedef __attribute__((ext_vector_type(4))) float f4v;

DEVI ushort f2bf(float f) {  // RTNE f32 -> bf16
  uint32_t x = __float_as_uint(f);
  x += 0x7fffu + ((x >> 16) & 1u);
  return (ushort)(x >> 16);
}

// ---------- f32 -> bf16 convert, n % 1024 == 0, grid = n/1024 ----------
__global__ __launch_bounds__(256) void cvt_kernel(const float* __restrict__ in,
                                                  ushort* __restrict__ out, int n) {
  int i = (blockIdx.x * 256 + threadIdx.x) * 4;
  if (i >= n) return;
  float4 v = *reinterpret_cast<const float4*>(in + i);
  ushort4 o;
  o.x = f2bf(v.x); o.y = f2bf(v.y); o.z = f2bf(v.z); o.w = f2bf(v.w);
  *reinterpret_cast<ushort4*>(out + i) = o;
}

// ---------- embedding + sinusoidal pos encoding, grid = 2048 rows ----------
__global__ __launch_bounds__(256) void embed_kernel(const int* __restrict__ ids,
                                                    const float* __restrict__ emb,
                                                    float* __restrict__ x) {
  int row = blockIdx.x;  // n*1024 + t
  int t = row & 1023;
  int id = ids[row];
  int d0 = threadIdx.x * 4;
  float4 e = *reinterpret_cast<const float4*>(emb + (size_t)id * 1024 + d0);
  float pe[4];
#pragma unroll
  for (int i = 0; i < 4; ++i) {
    int d = d0 + i;
    float dv = expf((float)(d & ~1) * (-9.210340371976184f / 1024.f));
    float ang = (float)t * dv;
    pe[i] = (d & 1) ? cosf(ang) : sinf(ang);
  }
  float4 o;
  o.x = e.x + pe[0]; o.y = e.y + pe[1]; o.z = e.z + pe[2]; o.w = e.w + pe[3];
  *reinterpret_cast<float4*>(x + (size_t)row * 1024 + d0) = o;
}

// ---------- LayerNorm (f32 in, bf16 out), grid = 2048 rows ----------
__global__ __launch_bounds__(256) void ln_kernel(const float* __restrict__ x,
                                                 const float* __restrict__ w,
                                                 const float* __restrict__ b,
                                                 ushort* __restrict__ out) {
  int row = blockIdx.x, tid = threadIdx.x;
  int lane = tid & 63, wid = tid >> 6;
  const float* xr = x + (size_t)row * 1024;
  float4 v = reinterpret_cast<const float4*>(xr)[tid];
  __shared__ float red[8];
  float s = v.x + v.y + v.z + v.w;
#pragma unroll
  for (int o = 32; o; o >>= 1) s += __shfl_xor(s, o);
  if (lane == 0) red[wid] = s;
  __syncthreads();
  float mean = (red[0] + red[1] + red[2] + red[3]) * (1.f / 1024.f);
  float d0 = v.x - mean, d1 = v.y - mean, d2 = v.z - mean, d3 = v.w - mean;
  float s2 = d0 * d0 + d1 * d1 + d2 * d2 + d3 * d3;
#pragma unroll
  for (int o = 32; o; o >>= 1) s2 += __shfl_xor(s2, o);
  if (lane == 0) red[4 + wid] = s2;
  __syncthreads();
  float var = (red[4] + red[5] + red[6] + red[7]) * (1.f / 1024.f);
  float rstd = rsqrtf(var + 1e-5f);
  float4 wv = reinterpret_cast<const float4*>(w)[tid];
  float4 bv = reinterpret_cast<const float4*>(b)[tid];
  ushort4 o;
  o.x = f2bf(d0 * rstd * wv.x + bv.x);
  o.y = f2bf(d1 * rstd * wv.y + bv.y);
  o.z = f2bf(d2 * rstd * wv.z + bv.z);
  o.w = f2bf(d3 * rstd * wv.w + bv.w);
  *reinterpret_cast<ushort4*>(out + (size_t)row * 1024 + tid * 4) = o;
}

// ---------- bf16 MFMA GEMM: C[M,N] = A[M,K] * Bw[N,K]^T, templated epilogue ----------
// 128x128 tile, BK=32, 256 threads = 4 waves (2x2), each wave 64x64 = 4x4 16x16 frags.
enum { EPI_QKV = 0, EPI_GELU = 1, EPI_RES = 2, EPI_BIAS = 3 };

template <int EPI>
__global__ __launch_bounds__(256) void gemm_kernel(const ushort* __restrict__ A,
                                                   const ushort* __restrict__ Bw,
                                                   const float* __restrict__ bias,
                                                   void* __restrict__ outp,
                                                   int M, int N, int K) {
  constexpr int LDT = 40;  // padded LDS row stride (ushorts); 80B keeps b128 16B-aligned
  __shared__ ushort As[128 * LDT];
  __shared__ ushort Bs[128 * LDT];
  int tid = threadIdx.x;
  int lane = tid & 63;
  int wid = tid >> 6, wr = wid >> 1, wc = wid & 1;
  int bm = blockIdx.x, bn = blockIdx.y;
  if constexpr (EPI == EPI_QKV) Bw += (size_t)blockIdx.z * (1024u * 1024u);

  const ushort* Ab = A + (size_t)(bm * 128) * K;
  const ushort* Bb = Bw + (size_t)(bn * 128) * K;

  f4v acc[4][4] = {};

  int lr = lane & 15;
  int lk = (lane >> 4) << 3;  // k-offset 0/8/16/24 within BK=32
  int r0 = tid >> 2;          // staging row within 64-row half
  int kc = (tid & 3) << 3;    // staging k-offset (8 bf16 = 16B chunks)
  uint4 ar[2], br[2];

  auto ldg = [&](int k0) {
#pragma unroll
    for (int j = 0; j < 2; ++j) {
      size_t ro = (size_t)(j * 64 + r0) * K + k0 + kc;
      ar[j] = *reinterpret_cast<const uint4*>(Ab + ro);
      br[j] = *reinterpret_cast<const uint4*>(Bb + ro);
    }
  };
  ldg(0);

  for (int k0 = 0; k0 < K; k0 += 32) {
    __syncthreads();  // previous iteration's frag reads complete
#pragma unroll
    for (int j = 0; j < 2; ++j) {
      int lo = (j * 64 + r0) * LDT + kc;
      *reinterpret_cast<uint4*>(&As[lo]) = ar[j];
      *reinterpret_cast<uint4*>(&Bs[lo]) = br[j];
    }
    __syncthreads();
    if (k0 + 32 < K) ldg(k0 + 32);  // prefetch next tile under MFMA work
    s8v af[4], bf[4];
#pragma unroll
    for (int mi = 0; mi < 4; ++mi)
      af[mi] = *reinterpret_cast<const s8v*>(&As[(wr * 64 + mi * 16 + lr) * LDT + lk]);
#pragma unroll
    for (int ni = 0; ni < 4; ++ni)
      bf[ni] = *reinterpret_cast<const s8v*>(&Bs[(wc * 64 + ni * 16 + lr) * LDT + lk]);
#pragma unroll
    for (int mi = 0; mi < 4; ++mi)
#pragma unroll
      for (int ni = 0; ni < 4; ++ni)
        acc[mi][ni] = __builtin_amdgcn_mfma_f32_16x16x32_bf16(af[mi], bf[ni], acc[mi][ni], 0, 0, 0);
  }

  // C/D layout (m89-verified): col = lane&15, row = (lane>>4)*4 + reg
  int row0 = bm * 128 + wr * 64 + ((lane >> 4) << 2);
  int col0 = bn * 128 + wc * 64 + lr;
#pragma unroll
  for (int mi = 0; mi < 4; ++mi) {
#pragma unroll
    for (int ni = 0; ni < 4; ++ni) {
#pragma unroll
      for (int r = 0; r < 4; ++r) {
        int gm = row0 + mi * 16 + r;
        int gn = col0 + ni * 16;
        float val = acc[mi][ni][r];
        if constexpr (EPI == EPI_QKV) {
          // scatter to q/k/v [2][16][1024][64]; z selects q/k/v
          float* o = (float*)outp + (size_t)blockIdx.z * 2097152;
          int nb = gm >> 10, t = gm & 1023;
          int hh = gn >> 6, dd = gn & 63;
          o[(size_t)nb * 1048576 + hh * 65536 + t * 64 + dd] = val;
        } else if constexpr (EPI == EPI_GELU) {
          float u = val + bias[gn];
          float g = 0.5f * u * (1.f + tanhf(0.7978845608f * (u + 0.044715f * u * u * u)));
          ((ushort*)outp)[(size_t)gm * N + gn] = f2bf(g);
        } else if constexpr (EPI == EPI_RES) {
          float* o = (float*)outp;
          size_t idx = (size_t)gm * N + gn;
          o[idx] += val + bias[gn];  // x = x + fc2(m) + b  (unique owner per element)
        } else {  // EPI_BIAS (readout)
          ((float*)outp)[(size_t)gm * N + gn] = val + bias[gn];
        }
      }
    }
  }
}

// ---------- fused causal attention, f32, online softmax ----------
// block = 256 thr = 4 waves; wave owns one q-row; lane = s (scores) / dv (PV).
// grid = N*H*256 row-quads = 8192. x[n,t,h*64+dv] += softmax(qk)*v (unique owner).
__global__ __launch_bounds__(256) void attn_kernel(const float* __restrict__ qg,
                                                   const float* __restrict__ kg,
                                                   const float* __restrict__ vg,
                                                   float* __restrict__ x) {
  __shared__ float Kt[64][65];  // +1 pad: scalar reads 2-way max
  __shared__ float Vt[64][65];
  __shared__ float ql[4][64];
  __shared__ float pl[4][64];
  int bx = blockIdx.x;
  int nh = bx >> 8, rb = bx & 255;
  int tid = threadIdx.x, lane = tid & 63, wid = tid >> 6;
  int r = rb * 4 + wid;
  size_t base = (size_t)nh * 65536;
  ql[wid][lane] = qg[base + (size_t)r * 64 + lane];
  float m_run = NEG_INF, l_run = 0.f, acc = 0.f;
  int ntiles = (rb * 4 + 67) >> 6;  // covers s <= r for all 4 rows
  for (int tile = 0; tile < ntiles; ++tile) {
    int s0 = tile << 6;
    __syncthreads();  // prior reads of Kt/Vt done (and ql visible on iter 0)
#pragma unroll
    for (int j = 0; j < 4; ++j) {
      int e = j * 256 + tid;  // 1024 float4 chunks for K and V tiles
      int ss = e >> 4, d0 = (e & 15) << 2;
      float4 kv = *reinterpret_cast<const float4*>(kg + base + (size_t)(s0 + ss) * 64 + d0);
      Kt[ss][d0] = kv.x; Kt[ss][d0 + 1] = kv.y; Kt[ss][d0 + 2] = kv.z; Kt[ss][d0 + 3] = kv.w;
      float4 vv = *reinterpret_cast<const float4*>(vg + base + (size_t)(s0 + ss) * 64 + d0);
      Vt[ss][d0] = vv.x; Vt[ss][d0 + 1] = vv.y; Vt[ss][d0 + 2] = vv.z; Vt[ss][d0 + 3] = vv.w;
    }
    __syncthreads();
    float dot = 0.f;  // lane's score vs s = s0+lane
#pragma unroll
    for (int d = 0; d < 64; ++d) dot += ql[wid][d] * Kt[lane][d];
    int sg = s0 + lane;
    bool valid = sg <= r;
    float sc = dot * 0.125f;  // 1/sqrt(64)
    float mx = valid ? sc : NEG_INF;
#pragma unroll
    for (int o = 32; o; o >>= 1) mx = fmaxf(mx, __shfl_xor(mx, o));
    float m_new = fmaxf(m_run, mx);
    float p = valid ? expf(sc - m_new) : 0.f;
    float ps = p;
#pragma unroll
    for (int o = 32; o; o >>= 1) ps += __shfl_xor(ps, o);
    float corr = expf(m_run - m_new);  // 0 on first tile (m_run = -inf)
    l_run = l_run * corr + ps;
    m_run = m_new;
    pl[wid][lane] = p;
    __syncthreads();  // order pl write -> read; Kt/Vt still read-only
    float av = 0.f;  // lane's output dim dv = lane
#pragma unroll
    for (int s = 0; s < 64; ++s) av += pl[wid][s] * Vt[s][lane];
    acc = acc * corr + av;
  }
  int n = nh >> 4, hh = nh & 15;
  size_t xi = ((size_t)(n * 1024 + r)) * 1024 + hh * 64 + lane;
  x[xi] += acc / l_run;
}

// ---------------------------------------------------------------------------
extern "C" void kernel_launch(void* const* d_in, const int* in_sizes, int n_in,
                              void* d_out, int out_size, void* d_ws, size_t ws_size,
                              hipStream_t stream) {
  const int*   ids  = (const int*)  d_in[0];
  const float* emb  = (const float*)d_in[1];
  const float* ln1w = (const float*)d_in[2];
  const float* ln1b = (const float*)d_in[3];
  const float* wq   = (const float*)d_in[4];
  const float* wk   = (const float*)d_in[5];
  const float* wv   = (const float*)d_in[6];
  const float* ln2w = (const float*)d_in[7];
  const float* ln2b = (const float*)d_in[8];
  const float* fc1w = (const float*)d_in[9];
  const float* fc1b = (const float*)d_in[10];
  const float* fc2w = (const float*)d_in[11];
  const float* fc2b = (const float*)d_in[12];
  const float* row_ = (const float*)d_in[13];
  const float* rob  = (const float*)d_in[14];
  (void)in_sizes; (void)n_in; (void)out_size; (void)ws_size;

  // ws carve (~148 MB total)
  char* p = (char*)d_ws;
  auto carve = [&](size_t bytes) {
    char* r = p;
    p += (bytes + 255) & ~(size_t)255;
    return (void*)r;
  };
  ushort* ro_bf   = (ushort*)carve(32000ull * 1024 * 2);  // readout weights bf16
  ushort* wqkv_bf = (ushort*)carve(3ull * 1024 * 1024 * 2);
  ushort* fc1_bf  = (ushort*)carve(4096ull * 1024 * 2);
  ushort* fc2_bf  = (ushort*)carve(4096ull * 1024 * 2);
  float*  x       = (float*) carve(2048ull * 1024 * 4);   // residual stream f32
  ushort* h       = (ushort*)carve(2048ull * 1024 * 2);   // LN out bf16
  float*  qkv     = (float*) carve(3ull * 2048 * 1024 * 4);
  ushort* mbuf    = (ushort*)carve(2048ull * 4096 * 2);   // gelu(fc1) bf16
  ushort* xb      = (ushort*)carve(2048ull * 1024 * 2);   // final x bf16

  cvt_kernel<<<32000 * 1024 / 1024, 256, 0, stream>>>(row_, ro_bf, 32000 * 1024);
  embed_kernel<<<2048, 256, 0, stream>>>(ids, emb, x);

  for (int l = 0; l < 8; ++l) {
    cvt_kernel<<<1024, 256, 0, stream>>>(wq + (size_t)l * 1048576, wqkv_bf, 1048576);
    cvt_kernel<<<1024, 256, 0, stream>>>(wk + (size_t)l * 1048576, wqkv_bf + 1048576, 1048576);
    cvt_kernel<<<1024, 256, 0, stream>>>(wv + (size_t)l * 1048576, wqkv_bf + 2097152, 1048576);
    cvt_kernel<<<4096, 256, 0, stream>>>(fc1w + (size_t)l * 4194304, fc1_bf, 4194304);
    cvt_kernel<<<4096, 256, 0, stream>>>(fc2w + (size_t)l * 4194304, fc2_bf, 4194304);

    ln_kernel<<<2048, 256, 0, stream>>>(x, ln1w + l * 1024, ln1b + l * 1024, h);
    gemm_kernel<EPI_QKV><<<dim3(16, 8, 3), 256, 0, stream>>>(h, wqkv_bf, nullptr, qkv,
                                                             2048, 1024, 1024);
    attn_kernel<<<8192, 256, 0, stream>>>(qkv, qkv + 2097152, qkv + 4194304, x);
    ln_kernel<<<2048, 256, 0, stream>>>(x, ln2w + l * 1024, ln2b + l * 1024, h);
    gemm_kernel<EPI_GELU><<<dim3(16, 32, 1), 256, 0, stream>>>(h, fc1_bf,
                                                               fc1b + (size_t)l * 4096, mbuf,
                                                               2048, 4096, 1024);
    gemm_kernel<EPI_RES><<<dim3(16, 8, 1), 256, 0, stream>>>(mbuf, fc2_bf,
                                                             fc2b + (size_t)l * 1024, x,
                                                             2048, 1024, 4096);
  }
  cvt_kernel<<<2048, 256, 0, stream>>>(x, xb, 2097152);
  gemm_kernel<EPI_BIAS><<<dim3(16, 250, 1), 256, 0, stream>>>(xb, ro_bf, rob, d_out,
                                                              2048, 32000, 1024);
}